// Round 1
// baseline (241.497 us; speedup 1.0000x reference)
//
#include <hip/hip_runtime.h>
#include <math.h>

#define TPB 256

typedef float vf4 __attribute__((ext_vector_type(4)));

// ---------------- LN over concat(emb_cause, emb_action) : rows of 1536 ----------------
__global__ void k_concat_ln(const float* __restrict__ ec, const float* __restrict__ ea,
                            const float* __restrict__ g, const float* __restrict__ bb,
                            float* __restrict__ o)
{
    int r = blockIdx.x, t = threadIdx.x;
    __shared__ float red[4];
    float v[6];
    float sum = 0.f;
#pragma unroll
    for (int j = 0; j < 6; ++j) {
        int c = t + j * TPB;
        float x = (c < 768) ? ec[r * 768 + c] : ea[r * 768 + (c - 768)];
        v[j] = x; sum += x;
    }
#pragma unroll
    for (int o_ = 32; o_ > 0; o_ >>= 1) sum += __shfl_xor(sum, o_);
    if ((t & 63) == 0) red[t >> 6] = sum;
    __syncthreads();
    sum = red[0] + red[1] + red[2] + red[3];
    float mean = sum * (1.0f / 1536.0f);
    __syncthreads();
    float s2 = 0.f;
#pragma unroll
    for (int j = 0; j < 6; ++j) { float d = v[j] - mean; s2 += d * d; }
#pragma unroll
    for (int o_ = 32; o_ > 0; o_ >>= 1) s2 += __shfl_xor(s2, o_);
    if ((t & 63) == 0) red[t >> 6] = s2;
    __syncthreads();
    s2 = red[0] + red[1] + red[2] + red[3];
    float rstd = rsqrtf(s2 * (1.0f / 1536.0f) + 1e-5f);
#pragma unroll
    for (int j = 0; j < 6; ++j) {
        int c = t + j * TPB;
        o[r * 1536 + c] = (v[j] - mean) * rstd * g[c] + bb[c];
    }
}

// ---------------- LN of ctx (768) -> two outputs (delta-LN, eff-LN) ----------------
__global__ void k_ln2(const float* __restrict__ x,
                      const float* __restrict__ dg, const float* __restrict__ db,
                      const float* __restrict__ eg, const float* __restrict__ eb,
                      float* __restrict__ od, float* __restrict__ oe)
{
    int r = blockIdx.x, t = threadIdx.x;
    __shared__ float red[4];
    float v[3];
    float sum = 0.f;
#pragma unroll
    for (int j = 0; j < 3; ++j) {
        int c = t + j * TPB;
        v[j] = x[r * 768 + c]; sum += v[j];
    }
#pragma unroll
    for (int o_ = 32; o_ > 0; o_ >>= 1) sum += __shfl_xor(sum, o_);
    if ((t & 63) == 0) red[t >> 6] = sum;
    __syncthreads();
    sum = red[0] + red[1] + red[2] + red[3];
    float mean = sum * (1.0f / 768.0f);
    __syncthreads();
    float s2 = 0.f;
#pragma unroll
    for (int j = 0; j < 3; ++j) { float d = v[j] - mean; s2 += d * d; }
#pragma unroll
    for (int o_ = 32; o_ > 0; o_ >>= 1) s2 += __shfl_xor(s2, o_);
    if ((t & 63) == 0) red[t >> 6] = s2;
    __syncthreads();
    s2 = red[0] + red[1] + red[2] + red[3];
    float rstd = rsqrtf(s2 * (1.0f / 768.0f) + 1e-5f);
#pragma unroll
    for (int j = 0; j < 3; ++j) {
        int c = t + j * TPB;
        float xh = (v[j] - mean) * rstd;
        od[r * 768 + c] = xh * dg[c] + db[c];
        oe[r * 768 + c] = xh * eg[c] + eb[c];
    }
}

// ---------------- split-K GEMM, X:(64,K) @ W:(K,N) -> part[s][64][N] ----------------
// grid (N/64, 12); 256 thr; 4x4 register tile per thread
__global__ void gemm64_partial(const float* __restrict__ X, const float* __restrict__ W,
                               float* __restrict__ part, int K, int N, int kslice)
{
    const int ct = blockIdx.x, s = blockIdx.y;
    const int t = threadIdx.x;
    const int tr4 = (t >> 4) << 2;   // row base 0..60
    const int tc4 = (t & 15) << 2;   // col base 0..60 in tile
    const int k0 = s * kslice;
    __shared__ float xs[32][64];
    __shared__ float wt[32][68];
    float acc[4][4] = {{0.f,0.f,0.f,0.f},{0.f,0.f,0.f,0.f},{0.f,0.f,0.f,0.f},{0.f,0.f,0.f,0.f}};
    for (int kc = 0; kc < kslice; kc += 32) {
        for (int n = t; n < 64 * 32; n += TPB) {
            int r = n >> 5, k = n & 31;
            xs[k][r] = X[r * K + k0 + kc + k];
        }
        for (int n = t; n < 32 * 64; n += TPB) {
            int k = n >> 6, c = n & 63;
            wt[k][c] = W[(k0 + kc + k) * N + ct * 64 + c];
        }
        __syncthreads();
#pragma unroll
        for (int k = 0; k < 32; ++k) {
            float4 xv = *(const float4*)&xs[k][tr4];
            float4 wv = *(const float4*)&wt[k][tc4];
            acc[0][0] += xv.x * wv.x; acc[0][1] += xv.x * wv.y; acc[0][2] += xv.x * wv.z; acc[0][3] += xv.x * wv.w;
            acc[1][0] += xv.y * wv.x; acc[1][1] += xv.y * wv.y; acc[1][2] += xv.y * wv.z; acc[1][3] += xv.y * wv.w;
            acc[2][0] += xv.z * wv.x; acc[2][1] += xv.z * wv.y; acc[2][2] += xv.z * wv.z; acc[2][3] += xv.z * wv.w;
            acc[3][0] += xv.w * wv.x; acc[3][1] += xv.w * wv.y; acc[3][2] += xv.w * wv.z; acc[3][3] += xv.w * wv.w;
        }
        __syncthreads();
    }
    float* pp = part + (s * 64 + tr4) * N + ct * 64 + tc4;
#pragma unroll
    for (int i = 0; i < 4; ++i)
#pragma unroll
        for (int j = 0; j < 4; ++j)
            pp[i * N + j] = acc[i][j];
}

// ---------------- epilogue: sum 12 partials + bias + activation ----------------
// act: 0 none, 1 exact GELU, 2 gate = 1 + tanh(silu(x))
__global__ void gemm64_epi(const float* __restrict__ part, const float* __restrict__ bias,
                           float* __restrict__ Y, int N, int act)
{
    int idx = blockIdx.x * TPB + threadIdx.x;
    if (idx >= 64 * N) return;
    int c = idx % N;
    float v = bias ? bias[c] : 0.0f;
#pragma unroll
    for (int s_ = 0; s_ < 12; ++s_) v += part[s_ * 64 * N + idx];
    if (act == 1) {
        v = 0.5f * v * (1.0f + erff(v * 0.70710678118654752f));
    } else if (act == 2) {
        float si = v / (1.0f + expf(-v));
        v = 1.0f + tanhf(si);
    }
    Y[idx] = v;
}

// ---------------- pooled_effect stage 1: partial sums over 64 q each ----------------
__global__ void k_pool1(const float* __restrict__ tok_effect, float* __restrict__ pp)
{
    int c = blockIdx.x * TPB + threadIdx.x;   // 0..767
    int b = blockIdx.y, qz = blockIdx.z;
    const float* base = tok_effect + (size_t)(b * 256 + qz * 64) * 768 + c;
    float s = 0.f;
#pragma unroll 8
    for (int q = 0; q < 64; ++q) s += base[(size_t)q * 768];
    pp[(qz * 64 + b) * 768 + c] = s;
}

// ---------------- pooled_effect stage 2 + e_shifted = pooled + delta_e ----------------
__global__ void k_pool2(const float* __restrict__ pp, const float* __restrict__ delta_e,
                        float* __restrict__ e_shifted)
{
    int c = blockIdx.x * TPB + threadIdx.x;
    int b = blockIdx.y;
    float s = pp[b * 768 + c] + pp[(64 + b) * 768 + c] + pp[(128 + b) * 768 + c] + pp[(192 + b) * 768 + c];
    e_shifted[b * 768 + c] = s * (1.0f / 256.0f) + delta_e[b * 768 + c];
}

// ---------------- wu[b][h][c] = sum_d v_w[c, h*128+d] * u[b, h*128+d] ----------------
// grid (8, 6): h, c-tile of 128
__global__ void k_wu(const float* __restrict__ u, const float* __restrict__ v_w,
                     float* __restrict__ wu)
{
    int h = blockIdx.x, ct = blockIdx.y;
    __shared__ float us[64][128];    // 32 KB
    for (int n = threadIdx.x; n < 8192; n += TPB) {
        int b = n >> 7, d = n & 127;
        us[b][d] = u[b * 1024 + h * 128 + d];
    }
    __syncthreads();
    int c = ct * 128 + (threadIdx.x >> 1);
    int bo = threadIdx.x & 1;
    const float* vr = v_w + (size_t)c * 1024 + h * 128;
    float acc[32];
#pragma unroll
    for (int i = 0; i < 32; ++i) acc[i] = 0.f;
    for (int d = 0; d < 128; d += 4) {
        float4 w4 = *(const float4*)(vr + d);
#pragma unroll
        for (int i = 0; i < 32; ++i) {
            const float* ub = &us[2 * i + bo][d];
            acc[i] += w4.x * ub[0] + w4.y * ub[1] + w4.z * ub[2] + w4.w * ub[3];
        }
    }
#pragma unroll
    for (int i = 0; i < 32; ++i) {
        int b = 2 * i + bo;
        wu[(b * 8 + h) * 768 + c] = acc[i];
    }
}

// ---------------- bias_s[b][h][k] = scale * tok_cause[b,k,:] . wu[b,:,h] ----------------
// grid (64, 4): b, k-tile of 64. scale = exp(logit_scale)/sqrt(128)
__global__ void k_bias(const float* __restrict__ tok_cause, const float* __restrict__ wu,
                       const float* __restrict__ ls_ptr, float* __restrict__ bias_s)
{
    int b = blockIdx.x, kt = blockIdx.y;
    __shared__ float wuh[8][768];    // 24 KB
    for (int n = threadIdx.x; n < 6144; n += TPB) {
        ((float*)wuh)[n] = wu[b * 6144 + n];
    }
    __syncthreads();
    float scale = expf(ls_ptr[0]) * 0.08838834764831845f;
    int wv = threadIdx.x >> 6, lane = threadIdx.x & 63;
#pragma unroll
    for (int it = 0; it < 4; ++it) {
        int kbase = kt * 64 + it * 16 + wv * 4;
        const float4* tr0 = (const float4*)(tok_cause + (size_t)(b * 256 + kbase + 0) * 768);
        const float4* tr1 = (const float4*)(tok_cause + (size_t)(b * 256 + kbase + 1) * 768);
        const float4* tr2 = (const float4*)(tok_cause + (size_t)(b * 256 + kbase + 2) * 768);
        const float4* tr3 = (const float4*)(tok_cause + (size_t)(b * 256 + kbase + 3) * 768);
        float acc[4][8];
#pragma unroll
        for (int kk = 0; kk < 4; ++kk)
#pragma unroll
            for (int hh = 0; hh < 8; ++hh) acc[kk][hh] = 0.f;
#pragma unroll
        for (int i = 0; i < 3; ++i) {
            int c4 = lane + 64 * i;
            float4 t0 = tr0[c4], t1 = tr1[c4], t2 = tr2[c4], t3 = tr3[c4];
#pragma unroll
            for (int hh = 0; hh < 8; ++hh) {
                float4 w4 = *(const float4*)&wuh[hh][c4 * 4];
                acc[0][hh] += t0.x * w4.x + t0.y * w4.y + t0.z * w4.z + t0.w * w4.w;
                acc[1][hh] += t1.x * w4.x + t1.y * w4.y + t1.z * w4.z + t1.w * w4.w;
                acc[2][hh] += t2.x * w4.x + t2.y * w4.y + t2.z * w4.z + t2.w * w4.w;
                acc[3][hh] += t3.x * w4.x + t3.y * w4.y + t3.z * w4.z + t3.w * w4.w;
            }
        }
#pragma unroll
        for (int kk = 0; kk < 4; ++kk)
#pragma unroll
            for (int hh = 0; hh < 8; ++hh) {
                float vv = acc[kk][hh];
#pragma unroll
                for (int o_ = 32; o_ > 0; o_ >>= 1) vv += __shfl_xor(vv, o_);
                if (lane == 0) bias_s[(b * 8 + hh) * 256 + (kbase + kk)] = vv * scale;
            }
    }
}

// ---------------- broadcast logit_bias[b,h,q,k] = bias_s[b,h,k] ----------------
__global__ void k_broadcast(const float* __restrict__ bias_s, float* __restrict__ out)
{
    const vf4* b4 = (const vf4*)bias_s;
    vf4* o4 = (vf4*)out;
    unsigned i = blockIdx.x * TPB + threadIdx.x;
#pragma unroll
    for (int j = 0; j < 16; ++j) {
        unsigned idx = i + (unsigned)j * (2048u * TPB);
        vf4 v = b4[(idx >> 14) * 64 + (idx & 63)];
        __builtin_nontemporal_store(v, &o4[idx]);
    }
}

extern "C" void kernel_launch(void* const* d_in, const int* in_sizes, int n_in,
                              void* d_out, int out_size, void* d_ws, size_t ws_size,
                              hipStream_t stream)
{
    (void)in_sizes; (void)n_in; (void)out_size; (void)ws_size;
    const float* emb_cause  = (const float*)d_in[0];
    const float* emb_action = (const float*)d_in[1];
    const float* tok_cause  = (const float*)d_in[2];
    const float* tok_effect = (const float*)d_in[3];
    const float* fuse_ln_g  = (const float*)d_in[4];
    const float* fuse_ln_b  = (const float*)d_in[5];
    const float* fuse_w1    = (const float*)d_in[6];
    const float* fuse_b1    = (const float*)d_in[7];
    const float* fuse_w2    = (const float*)d_in[8];
    const float* fuse_b2    = (const float*)d_in[9];
    const float* delta_ln_g = (const float*)d_in[10];
    const float* delta_ln_b = (const float*)d_in[11];
    const float* delta_w    = (const float*)d_in[12];
    const float* delta_b    = (const float*)d_in[13];
    const float* qg_w       = (const float*)d_in[14];
    const float* qg_b       = (const float*)d_in[15];
    const float* kg_w       = (const float*)d_in[16];
    const float* kg_b       = (const float*)d_in[17];
    const float* eff_ln_g   = (const float*)d_in[18];
    const float* eff_ln_b   = (const float*)d_in[19];
    const float* eff_w1     = (const float*)d_in[20];
    const float* eff_b1     = (const float*)d_in[21];
    const float* eff_w2     = (const float*)d_in[22];
    const float* eff_b2     = (const float*)d_in[23];
    const float* u_w        = (const float*)d_in[24];
    const float* v_w        = (const float*)d_in[25];
    const float* logit_sc   = (const float*)d_in[26];

    float* ws = (float*)d_ws;
    float* cat_ln = ws + 0;        // 64*1536
    float* h_buf  = ws + 98304;    // 64*768
    float* ctx    = ws + 147456;   // 64*768
    float* dln    = ws + 196608;   // 64*768
    float* eln    = ws + 245760;   // 64*768
    float* eh     = ws + 294912;   // 64*768
    float* u_buf  = ws + 344064;   // 64*1024
    float* wu     = ws + 409600;   // 64*8*768
    float* pp     = ws + 802816;   // 4*64*768
    float* part   = ws + 999424;   // 12*64*1024
    float* bias_s = ws + 1785856;  // 64*8*256

    float* out    = (float*)d_out;
    float* out_qg = out + 0;
    float* out_kg = out + 65536;
    float* out_es = out + 131072;
    float* out_de = out + 180224;
    float* out_lb = out + 229376;
    float* out_ep = out + 33783808;

    // ctx chain
    k_concat_ln<<<64, TPB, 0, stream>>>(emb_cause, emb_action, fuse_ln_g, fuse_ln_b, cat_ln);
    gemm64_partial<<<dim3(12, 12), TPB, 0, stream>>>(cat_ln, fuse_w1, part, 1536, 768, 128);
    gemm64_epi<<<192, TPB, 0, stream>>>(part, fuse_b1, h_buf, 768, 1);
    gemm64_partial<<<dim3(12, 12), TPB, 0, stream>>>(h_buf, fuse_w2, part, 768, 768, 64);
    gemm64_epi<<<192, TPB, 0, stream>>>(part, fuse_b2, ctx, 768, 0);
    k_ln2<<<64, TPB, 0, stream>>>(ctx, delta_ln_g, delta_ln_b, eff_ln_g, eff_ln_b, dln, eln);

    // delta_e -> out
    gemm64_partial<<<dim3(12, 12), TPB, 0, stream>>>(dln, delta_w, part, 768, 768, 64);
    gemm64_epi<<<192, TPB, 0, stream>>>(part, delta_b, out_de, 768, 0);

    // pooled effect + e_shifted -> out
    k_pool1<<<dim3(3, 64, 4), TPB, 0, stream>>>(tok_effect, pp);
    k_pool2<<<dim3(3, 64), TPB, 0, stream>>>(pp, out_de, out_es);

    // effect_pred -> out
    gemm64_partial<<<dim3(12, 12), TPB, 0, stream>>>(eln, eff_w1, part, 768, 768, 64);
    gemm64_epi<<<192, TPB, 0, stream>>>(part, eff_b1, eh, 768, 1);
    gemm64_partial<<<dim3(12, 12), TPB, 0, stream>>>(eh, eff_w2, part, 768, 768, 64);
    gemm64_epi<<<192, TPB, 0, stream>>>(part, eff_b2, out_ep, 768, 0);

    // gates -> out
    gemm64_partial<<<dim3(16, 12), TPB, 0, stream>>>(ctx, qg_w, part, 768, 1024, 64);
    gemm64_epi<<<256, TPB, 0, stream>>>(part, qg_b, out_qg, 1024, 2);
    gemm64_partial<<<dim3(16, 12), TPB, 0, stream>>>(ctx, kg_w, part, 768, 1024, 64);
    gemm64_epi<<<256, TPB, 0, stream>>>(part, kg_b, out_kg, 1024, 2);

    // u = e_shifted @ u_w (no bias)
    gemm64_partial<<<dim3(16, 12), TPB, 0, stream>>>(out_es, u_w, part, 768, 1024, 64);
    gemm64_epi<<<256, TPB, 0, stream>>>(part, (const float*)nullptr, u_buf, 1024, 0);

    // fold u into v_w, then bias, then broadcast
    k_wu<<<dim3(8, 6), TPB, 0, stream>>>(u_buf, v_w, wu);
    k_bias<<<dim3(64, 4), TPB, 0, stream>>>(tok_cause, wu, logit_sc, bias_s);
    k_broadcast<<<2048, TPB, 0, stream>>>(bias_s, out_lb);
}

// Round 2
// 154.316 us; speedup vs baseline: 1.5649x; 1.5649x over previous
//
#include <hip/hip_runtime.h>
#include <math.h>

#define TPB 256

typedef float vf4 __attribute__((ext_vector_type(4)));

// ============ front: concat-LN (blocks 0..63) + pool1 partials (blocks 64..831) ============
__global__ __launch_bounds__(256) void k_front(const float* __restrict__ ec, const float* __restrict__ ea,
                        const float* __restrict__ g, const float* __restrict__ bb,
                        float* __restrict__ o,
                        const float* __restrict__ tok_effect, float* __restrict__ pp)
{
    int t = threadIdx.x;
    if (blockIdx.x < 64) {
        int r = blockIdx.x;
        __shared__ float red[4];
        float v[6];
        float sum = 0.f;
#pragma unroll
        for (int j = 0; j < 6; ++j) {
            int c = t + j * TPB;
            float x = (c < 768) ? ec[r * 768 + c] : ea[r * 768 + (c - 768)];
            v[j] = x; sum += x;
        }
#pragma unroll
        for (int o_ = 32; o_ > 0; o_ >>= 1) sum += __shfl_xor(sum, o_);
        if ((t & 63) == 0) red[t >> 6] = sum;
        __syncthreads();
        sum = red[0] + red[1] + red[2] + red[3];
        float mean = sum * (1.0f / 1536.0f);
        __syncthreads();
        float s2 = 0.f;
#pragma unroll
        for (int j = 0; j < 6; ++j) { float d = v[j] - mean; s2 += d * d; }
#pragma unroll
        for (int o_ = 32; o_ > 0; o_ >>= 1) s2 += __shfl_xor(s2, o_);
        if ((t & 63) == 0) red[t >> 6] = s2;
        __syncthreads();
        s2 = red[0] + red[1] + red[2] + red[3];
        float rstd = rsqrtf(s2 * (1.0f / 1536.0f) + 1e-5f);
#pragma unroll
        for (int j = 0; j < 6; ++j) {
            int c = t + j * TPB;
            o[r * 1536 + c] = (v[j] - mean) * rstd * g[c] + bb[c];
        }
    } else {
        int m = blockIdx.x - 64;           // 0..767
        int cchunk = m % 3;
        int b = (m / 3) % 64;
        int qz = m / 192;
        int c = cchunk * TPB + t;
        const float* base = tok_effect + (size_t)(b * 256 + qz * 64) * 768 + c;
        float s = 0.f;
#pragma unroll 8
        for (int q = 0; q < 64; ++q) s += base[(size_t)q * 768];
        pp[(qz * 64 + b) * 768 + c] = s;
    }
}

// ============ batched split-K GEMM partial: X:(64,K) @ W:(K,Nseg) ============
struct GArgs {
    const float* X[4]; const float* W[4];
    int tile0[5];      // cumulative col-tile starts, tile0[nseg] = total tiles
    int nseg; int K; int kslice; int totN;
    float* part;
};

__global__ __launch_bounds__(256) void k_gemmp(GArgs A)
{
    const int ct = blockIdx.x, s = blockIdx.y;
    const int t = threadIdx.x;
    int seg = 0;
    while (seg + 1 < A.nseg && ct >= A.tile0[seg + 1]) ++seg;
    const float* __restrict__ X = A.X[seg];
    const float* __restrict__ W = A.W[seg];
    const int N = (A.tile0[seg + 1] - A.tile0[seg]) * 64;
    const int cb = (ct - A.tile0[seg]) * 64;
    const int tr4 = (t >> 4) << 2;
    const int tc4 = (t & 15) << 2;
    const int k0 = s * A.kslice;
    __shared__ float xs[32][64];
    __shared__ float wt[32][68];
    float acc[4][4] = {{0.f,0.f,0.f,0.f},{0.f,0.f,0.f,0.f},{0.f,0.f,0.f,0.f},{0.f,0.f,0.f,0.f}};
    for (int kc = 0; kc < A.kslice; kc += 32) {
        for (int n = t; n < 64 * 32; n += TPB) {
            int r = n >> 5, k = n & 31;
            xs[k][r] = X[r * A.K + k0 + kc + k];
        }
        for (int n = t; n < 32 * 64; n += TPB) {
            int k = n >> 6, c = n & 63;
            wt[k][c] = W[(size_t)(k0 + kc + k) * N + cb + c];
        }
        __syncthreads();
#pragma unroll
        for (int k = 0; k < 32; ++k) {
            float4 xv = *(const float4*)&xs[k][tr4];
            float4 wv = *(const float4*)&wt[k][tc4];
            acc[0][0] += xv.x * wv.x; acc[0][1] += xv.x * wv.y; acc[0][2] += xv.x * wv.z; acc[0][3] += xv.x * wv.w;
            acc[1][0] += xv.y * wv.x; acc[1][1] += xv.y * wv.y; acc[1][2] += xv.y * wv.z; acc[1][3] += xv.y * wv.w;
            acc[2][0] += xv.z * wv.x; acc[2][1] += xv.z * wv.y; acc[2][2] += xv.z * wv.z; acc[2][3] += xv.z * wv.w;
            acc[3][0] += xv.w * wv.x; acc[3][1] += xv.w * wv.y; acc[3][2] += xv.w * wv.z; acc[3][3] += xv.w * wv.w;
        }
        __syncthreads();
    }
    float* pp = A.part + (size_t)(s * 64 + tr4) * A.totN + ct * 64 + tc4;
#pragma unroll
    for (int i = 0; i < 4; ++i)
#pragma unroll
        for (int j = 0; j < 4; ++j)
            pp[i * A.totN + j] = acc[i][j];
}

// ============ batched epilogue: sum S partials + bias + act; optional e_shifted fuse ============
struct EpiArgs {
    const float* part; const float* pp;
    const float* bias[4]; float* Y[4]; float* Y2[4];
    int col0[5]; int act[4]; int nseg; int totN; int S;
};

__global__ __launch_bounds__(256) void k_epi(EpiArgs A)
{
    int idx = blockIdx.x * TPB + threadIdx.x;
    if (idx >= 64 * A.totN) return;
    int r = idx / A.totN;
    int c = idx - r * A.totN;
    float v = 0.f;
    for (int s = 0; s < A.S; ++s) v += A.part[(size_t)(s * 64 + r) * A.totN + c];
    int seg = 0;
    while (seg + 1 < A.nseg && c >= A.col0[seg + 1]) ++seg;
    int cl = c - A.col0[seg];
    if (A.bias[seg]) v += A.bias[seg][cl];
    int act = A.act[seg];
    if (act == 1) {
        v = 0.5f * v * (1.0f + erff(v * 0.70710678118654752f));
    } else if (act == 2) {
        float si = v / (1.0f + expf(-v));
        v = 1.0f + tanhf(si);
    }
    int n = A.col0[seg + 1] - A.col0[seg];
    A.Y[seg][(size_t)r * n + cl] = v;
    if (A.Y2[seg]) {
        float s4 = A.pp[r * 768 + cl] + A.pp[(64 + r) * 768 + cl]
                 + A.pp[(128 + r) * 768 + cl] + A.pp[(192 + r) * 768 + cl];
        A.Y2[seg][(size_t)r * n + cl] = s4 * (1.0f / 256.0f) + v;
    }
}

// ============ fuse2 epilogue + dual LN (ctx -> dln, eln) ============
__global__ __launch_bounds__(256) void k_epi_ln(const float* __restrict__ part, const float* __restrict__ b2,
                         const float* __restrict__ dg, const float* __restrict__ db,
                         const float* __restrict__ eg, const float* __restrict__ eb,
                         float* __restrict__ ctx, float* __restrict__ od, float* __restrict__ oe)
{
    int r = blockIdx.x, t = threadIdx.x;
    __shared__ float red[4];
    float v[3];
    float sum = 0.f;
#pragma unroll
    for (int j = 0; j < 3; ++j) {
        int c = t + j * TPB;
        float x = b2[c];
#pragma unroll
        for (int s = 0; s < 12; ++s) x += part[(s * 64 + r) * 768 + c];
        v[j] = x; sum += x;
        ctx[r * 768 + c] = x;
    }
#pragma unroll
    for (int o_ = 32; o_ > 0; o_ >>= 1) sum += __shfl_xor(sum, o_);
    if ((t & 63) == 0) red[t >> 6] = sum;
    __syncthreads();
    sum = red[0] + red[1] + red[2] + red[3];
    float mean = sum * (1.0f / 768.0f);
    __syncthreads();
    float s2 = 0.f;
#pragma unroll
    for (int j = 0; j < 3; ++j) { float d = v[j] - mean; s2 += d * d; }
#pragma unroll
    for (int o_ = 32; o_ > 0; o_ >>= 1) s2 += __shfl_xor(s2, o_);
    if ((t & 63) == 0) red[t >> 6] = s2;
    __syncthreads();
    s2 = red[0] + red[1] + red[2] + red[3];
    float rstd = rsqrtf(s2 * (1.0f / 768.0f) + 1e-5f);
#pragma unroll
    for (int j = 0; j < 3; ++j) {
        int c = t + j * TPB;
        float xh = (v[j] - mean) * rstd;
        od[r * 768 + c] = xh * dg[c] + db[c];
        oe[r * 768 + c] = xh * eg[c] + eb[c];
    }
}

// ============ wu[b][h][c] = sum_d v_w[c, h*128+d] * u[b, h*128+d] ============
// grid (8 h, 12 c-tiles of 64)
__global__ __launch_bounds__(256) void k_wu(const float* __restrict__ u, const float* __restrict__ v_w,
                     float* __restrict__ wu)
{
    int h = blockIdx.x, ct = blockIdx.y;
    __shared__ float us[64][132];     // padded: rows land on distinct banks
    for (int n = threadIdx.x; n < 8192; n += TPB) {
        int b = n >> 7, d = n & 127;
        us[b][d] = u[b * 1024 + h * 128 + d];
    }
    __syncthreads();
    int c = ct * 64 + (threadIdx.x >> 2);
    int bo = threadIdx.x & 3;
    const float* vr = v_w + (size_t)c * 1024 + h * 128;
    float acc[16];
#pragma unroll
    for (int i = 0; i < 16; ++i) acc[i] = 0.f;
    for (int d = 0; d < 128; d += 4) {
        float4 w4 = *(const float4*)(vr + d);
#pragma unroll
        for (int i = 0; i < 16; ++i) {
            const float* ub = &us[4 * i + bo][d];
            acc[i] += w4.x * ub[0] + w4.y * ub[1] + w4.z * ub[2] + w4.w * ub[3];
        }
    }
#pragma unroll
    for (int i = 0; i < 16; ++i) {
        int b = 4 * i + bo;
        wu[(b * 8 + h) * 768 + c] = acc[i];
    }
}

// ============ bias_s[b][h][k] = scale * tok_cause[b,k,:] . wu[b,h,:] ============
// grid (64 b, 16 k-tiles of 16 rows); wu cached in registers per lane
__global__ __launch_bounds__(256) void k_bias2(const float* __restrict__ tok_cause, const float* __restrict__ wu,
                        const float* __restrict__ ls_ptr, float* __restrict__ bias_s)
{
    int b = blockIdx.x, kt = blockIdx.y;
    __shared__ float wuh[8][768];     // 24 KB
    for (int n = threadIdx.x; n < 6144; n += TPB)
        ((float*)wuh)[n] = wu[b * 6144 + n];
    __syncthreads();
    const int lane = threadIdx.x & 63, w = threadIdx.x >> 6;
    float4 wur[3][8];
#pragma unroll
    for (int j = 0; j < 3; ++j)
#pragma unroll
        for (int h = 0; h < 8; ++h)
            wur[j][h] = *(const float4*)&wuh[h][(lane + 64 * j) * 4];
    float scale = expf(ls_ptr[0]) * 0.08838834764831845f;
#pragma unroll
    for (int rr = 0; rr < 4; ++rr) {
        int row = kt * 16 + w * 4 + rr;
        const float4* tr = (const float4*)(tok_cause + ((size_t)b * 256 + row) * 768);
        float4 t0 = tr[lane], t1 = tr[lane + 64], t2 = tr[lane + 128];
        float acc[8];
#pragma unroll
        for (int h = 0; h < 8; ++h) {
            acc[h] = t0.x * wur[0][h].x + t0.y * wur[0][h].y + t0.z * wur[0][h].z + t0.w * wur[0][h].w
                   + t1.x * wur[1][h].x + t1.y * wur[1][h].y + t1.z * wur[1][h].z + t1.w * wur[1][h].w
                   + t2.x * wur[2][h].x + t2.y * wur[2][h].y + t2.z * wur[2][h].z + t2.w * wur[2][h].w;
        }
#pragma unroll
        for (int h = 0; h < 8; ++h) {
            float vv = acc[h];
#pragma unroll
            for (int o_ = 32; o_ > 0; o_ >>= 1) vv += __shfl_xor(vv, o_);
            if (lane == 0) bias_s[(b * 8 + h) * 256 + row] = vv * scale;
        }
    }
}

// ============ broadcast logit_bias[b,h,q,k] = bias_s[b,h,k] ============
__global__ __launch_bounds__(256) void k_broadcast(const float* __restrict__ bias_s, float* __restrict__ out)
{
    const vf4* b4 = (const vf4*)bias_s;
    vf4* o4 = (vf4*)out;
    unsigned i = blockIdx.x * TPB + threadIdx.x;
#pragma unroll
    for (int j = 0; j < 16; ++j) {
        unsigned idx = i + (unsigned)j * (2048u * TPB);
        vf4 v = b4[(idx >> 14) * 64 + (idx & 63)];
        __builtin_nontemporal_store(v, &o4[idx]);
    }
}

extern "C" void kernel_launch(void* const* d_in, const int* in_sizes, int n_in,
                              void* d_out, int out_size, void* d_ws, size_t ws_size,
                              hipStream_t stream)
{
    (void)in_sizes; (void)n_in; (void)out_size; (void)ws_size;
    const float* emb_cause  = (const float*)d_in[0];
    const float* emb_action = (const float*)d_in[1];
    const float* tok_cause  = (const float*)d_in[2];
    const float* tok_effect = (const float*)d_in[3];
    const float* fuse_ln_g  = (const float*)d_in[4];
    const float* fuse_ln_b  = (const float*)d_in[5];
    const float* fuse_w1    = (const float*)d_in[6];
    const float* fuse_b1    = (const float*)d_in[7];
    const float* fuse_w2    = (const float*)d_in[8];
    const float* fuse_b2    = (const float*)d_in[9];
    const float* delta_ln_g = (const float*)d_in[10];
    const float* delta_ln_b = (const float*)d_in[11];
    const float* delta_w    = (const float*)d_in[12];
    const float* delta_b    = (const float*)d_in[13];
    const float* qg_w       = (const float*)d_in[14];
    const float* qg_b       = (const float*)d_in[15];
    const float* kg_w       = (const float*)d_in[16];
    const float* kg_b       = (const float*)d_in[17];
    const float* eff_ln_g   = (const float*)d_in[18];
    const float* eff_ln_b   = (const float*)d_in[19];
    const float* eff_w1     = (const float*)d_in[20];
    const float* eff_b1     = (const float*)d_in[21];
    const float* eff_w2     = (const float*)d_in[22];
    const float* eff_b2     = (const float*)d_in[23];
    const float* u_w        = (const float*)d_in[24];
    const float* v_w        = (const float*)d_in[25];
    const float* logit_sc   = (const float*)d_in[26];

    float* ws = (float*)d_ws;
    float* cat_ln = ws + 0;        // 64*1536
    float* h_buf  = ws + 98304;    // 64*768
    float* ctx    = ws + 147456;   // 64*768
    float* dln    = ws + 196608;   // 64*768
    float* eln    = ws + 245760;   // 64*768
    float* eh     = ws + 294912;   // 64*768
    float* u_buf  = ws + 344064;   // 64*1024
    float* wu     = ws + 409600;   // 64*8*768
    float* pp     = ws + 802816;   // 4*64*768
    float* bias_s = ws + 999424;   // 64*8*256  (end: 1130496 floats = 4.5 MB)

    float* out    = (float*)d_out;
    float* out_qg = out + 0;
    float* out_kg = out + 65536;
    float* out_es = out + 131072;
    float* out_de = out + 180224;
    float* out_lb = out + 229376;
    float* out_ep = out + 33783808;

    // split-K scratch lives in the tail of logit_bias (overwritten by k_broadcast last)
    float* part = out_lb + 20000000;   // 13.5M floats available; need max 2.75M

    // 1) concat-LN + pool1 partials
    k_front<<<832, TPB, 0, stream>>>(emb_cause, emb_action, fuse_ln_g, fuse_ln_b, cat_ln,
                                     tok_effect, pp);

    // 2-3) fuse1: cat_ln @ fuse_w1 + GELU
    {
        GArgs A = {};
        A.X[0] = cat_ln; A.W[0] = fuse_w1;
        A.tile0[0] = 0; A.tile0[1] = 12;
        A.nseg = 1; A.K = 1536; A.kslice = 128; A.totN = 768; A.part = part;
        k_gemmp<<<dim3(12, 12), TPB, 0, stream>>>(A);
        EpiArgs E = {};
        E.part = part; E.pp = nullptr;
        E.bias[0] = fuse_b1; E.Y[0] = h_buf; E.Y2[0] = nullptr;
        E.col0[0] = 0; E.col0[1] = 768; E.act[0] = 1;
        E.nseg = 1; E.totN = 768; E.S = 12;
        k_epi<<<192, TPB, 0, stream>>>(E);
    }

    // 4-5) fuse2: h @ fuse_w2, epilogue fused with dual-LN
    {
        GArgs A = {};
        A.X[0] = h_buf; A.W[0] = fuse_w2;
        A.tile0[0] = 0; A.tile0[1] = 12;
        A.nseg = 1; A.K = 768; A.kslice = 64; A.totN = 768; A.part = part;
        k_gemmp<<<dim3(12, 12), TPB, 0, stream>>>(A);
        k_epi_ln<<<64, TPB, 0, stream>>>(part, fuse_b2, delta_ln_g, delta_ln_b,
                                         eff_ln_g, eff_ln_b, ctx, dln, eln);
    }

    // 6-7) batch A: delta (dln), eff1+GELU (eln), q-gate (ctx), k-gate (ctx)
    {
        GArgs A = {};
        A.X[0] = dln;  A.W[0] = delta_w;
        A.X[1] = eln;  A.W[1] = eff_w1;
        A.X[2] = ctx;  A.W[2] = qg_w;
        A.X[3] = ctx;  A.W[3] = kg_w;
        A.tile0[0] = 0; A.tile0[1] = 12; A.tile0[2] = 24; A.tile0[3] = 40; A.tile0[4] = 56;
        A.nseg = 4; A.K = 768; A.kslice = 64; A.totN = 3584; A.part = part;
        k_gemmp<<<dim3(56, 12), TPB, 0, stream>>>(A);
        EpiArgs E = {};
        E.part = part; E.pp = pp;
        E.bias[0] = delta_b; E.Y[0] = out_de; E.Y2[0] = out_es; E.act[0] = 0;  // + e_shifted fuse
        E.bias[1] = eff_b1;  E.Y[1] = eh;     E.Y2[1] = nullptr; E.act[1] = 1;
        E.bias[2] = qg_b;    E.Y[2] = out_qg; E.Y2[2] = nullptr; E.act[2] = 2;
        E.bias[3] = kg_b;    E.Y[3] = out_kg; E.Y2[3] = nullptr; E.act[3] = 2;
        E.col0[0] = 0; E.col0[1] = 768; E.col0[2] = 1536; E.col0[3] = 2560; E.col0[4] = 3584;
        E.nseg = 4; E.totN = 3584; E.S = 12;
        k_epi<<<896, TPB, 0, stream>>>(E);
    }

    // 8-9) batch B: eff2 (eh), u (e_shifted)
    {
        GArgs A = {};
        A.X[0] = eh;     A.W[0] = eff_w2;
        A.X[1] = out_es; A.W[1] = u_w;
        A.tile0[0] = 0; A.tile0[1] = 12; A.tile0[2] = 28;
        A.nseg = 2; A.K = 768; A.kslice = 64; A.totN = 1792; A.part = part;
        k_gemmp<<<dim3(28, 12), TPB, 0, stream>>>(A);
        EpiArgs E = {};
        E.part = part; E.pp = nullptr;
        E.bias[0] = eff_b2;  E.Y[0] = out_ep; E.Y2[0] = nullptr; E.act[0] = 0;
        E.bias[1] = nullptr; E.Y[1] = u_buf;  E.Y2[1] = nullptr; E.act[1] = 0;
        E.col0[0] = 0; E.col0[1] = 768; E.col0[2] = 1792;
        E.nseg = 2; E.totN = 1792; E.S = 12;
        k_epi<<<448, TPB, 0, stream>>>(E);
    }

    // 10-12) fold u into v_w; per-(b,h,k) bias; broadcast
    k_wu<<<dim3(8, 12), TPB, 0, stream>>>(u_buf, v_w, wu);
    k_bias2<<<dim3(64, 16), TPB, 0, stream>>>(tok_cause, wu, logit_sc, bias_s);
    k_broadcast<<<2048, TPB, 0, stream>>>(bias_s, out_lb);
}